// Round 1
// baseline (275.491 us; speedup 1.0000x reference)
//
#include <hip/hip_runtime.h>

// SSIM-like loss, factored form:
//   term_n uses 3^n * (ZrV)^(n+1) (ZcH)^(n+1) (channel_sum): ONE vertical and ONE
//   horizontal (2h+1)-tap conv with exact edge-clipped weight rows. Weight rows are
//   now a compile-time __constant__ table (no per-block recurrence).
//   Geometry: 32x32 output tile, 48x48 window (was 64x32 / 80x48) -> LDS 20,480 B
//   -> 8 blocks/CU (was 4). fp32 moment partials, fp64 from wave reduction onward.
//   Accumulation: 64 slots per sample; wave-shfl block reduction.

typedef float v2f __attribute__((ext_vector_type(2)));
typedef float v4f __attribute__((ext_vector_type(4)));

#define BSTR 50     // buf float2 stride (even -> 16B-aligned rows for b128; +4-bank row skew)

#define PC 0.19487473f
#define QC 0.23021731f

#define NSLOT 64    // accumulation slots per sample

// ---- compile-time clipped 1-D weight rows: w[H-1][d*T + k], T = 2H+1,
//      d = dist to edge (0..H-1), d = H = interior row. Same recurrence the
//      device code used, evaluated at compile time.
struct WtTables { float w[8][153]; };
static constexpr WtTables make_tables() {
  WtTables t{};
  for (int H = 1; H <= 8; ++H) {
    const int T = 2 * H + 1;
    for (int d = 0; d <= H; ++d) {
      float Wd[17] = {};
      for (int k = 0; k < T; ++k) Wd[k] = (k == H) ? 1.f : 0.f;
      const int kmin = H - d;
      for (int m = 0; m < H; ++m) {
        float prev = 0.f;
        for (int k = kmin; k < T; ++k) {
          const float cur = Wd[k];
          const float nxt = (k < T - 1) ? Wd[k + 1] : 0.f;
          Wd[k] = QC * cur + PC * (prev + nxt);
          prev = cur;
        }
      }
      for (int k = 0; k < T; ++k) t.w[H - 1][d * T + k] = Wd[k];
    }
  }
  return t;
}
__constant__ WtTables WTAB = make_tables();

struct SharedMem {
  v2f buf[48 * BSTR];   // 19,200 B  input window -> H output (in place)
  double wred[4 * 5];   //    160 B  per-wave partials
  float Wt[153];        //    612 B  clipped weight rows (edge blocks only)
};                      // 19,972 B -> 20,480 granule -> 8 blocks/CU

__global__ __launch_bounds__(256) void ssim_zero(double* acc) {
  for (int i = threadIdx.x; i < 8 * NSLOT * 5; i += 256) acc[i] = 0.0;
}

template <int H>
__device__ __forceinline__ void body(SharedMem& sm, int oy, int ox, int tr, int tc,
                                     const float* __restrict__ xp,
                                     const float* __restrict__ yp,
                                     double* __restrict__ accn) {
  constexpr int T = 2 * H + 1;
  constexpr int n = H - 1;
  constexpr int R0 = 8 - H, R1 = 39 + H;            // used window rows (0..47)
  const int tid = threadIdx.x;
  const bool rowEdge = (tr == 0) | (tr == 31);
  const bool colEdge = (tc == 0) | (tc == 31);

  // ---- load: window row r <-> gy=oy+r-8, col cell w <-> gx=ox+w-8; zeros outside ----
  {
    constexpr int CC0 = (8 - H) >> 2, CC1 = (39 + H) >> 2;   // used 4-cell chunks
    const size_t base = (size_t)n * 3145728u;
    for (int c = tid; c < 576; c += 256) {        // 48 rows x 12 chunks
      const int row = c / 12;
      const int c4 = c - row * 12;
      if (row < R0 || row > R1 || c4 < CC0 || c4 > CC1) continue;
      const int gy = oy + row - 8;
      const int gx0 = ox + c4 * 4 - 8;
      v4f sx = {0.f, 0.f, 0.f, 0.f}, sy = {0.f, 0.f, 0.f, 0.f};
      if (((unsigned)gy < 1024u) && ((unsigned)gx0 < 1024u)) {
        const size_t off = base + (size_t)gy * 1024u + (unsigned)gx0;
        const v4f* px = (const v4f*)(xp + off);
        const v4f* py = (const v4f*)(yp + off);
        sx = px[0] + px[262144] + px[524288];      // 3-channel sum
        sy = py[0] + py[262144] + py[524288];
      }
      v4f* d = (v4f*)(sm.buf + row * BSTR + c4 * 4);
      d[0] = (v4f){sx.x, sy.x, sx.y, sy.y};
      d[1] = (v4f){sx.z, sy.z, sx.w, sy.w};
    }
  }
  // ---- edge blocks stage the weight table in LDS (dynamic per-lane indexing) ----
  if (rowEdge | colEdge) {
    for (int i = tid; i < (H + 1) * T; i += 256) sm.Wt[i] = WTAB.w[n][i];
  }
  __syncthreads();

  // ---- H pass IN PLACE: wave g owns col-group g (8 out cols), lane = window row ----
  {
    const int g = tid >> 6;              // col-group 0..3 (wave-uniform)
    const int i0 = tid & 63;             // window row
    constexpr int I0 = (8 - H) >> 1, I1 = (15 + H) >> 1;   // b128 read range
    const bool val = (i0 >= R0) & (i0 <= R1);
    v2f o[8] = {};
    if (val) {
      const v4f* s4 = (const v4f*)(sm.buf + i0 * BSTR + g * 8);
      v2f win[24];
#pragma unroll
      for (int i = I0; i <= I1; ++i) {
        const v4f t = s4[i];
        win[2 * i] = (v2f){t.x, t.y};
        win[2 * i + 1] = (v2f){t.z, t.w};
      }
      if (!colEdge) {
#pragma unroll
        for (int k = 0; k < T; ++k) {
          const float cw = WTAB.w[n][H * T + k];   // compile-time-constant index
#pragma unroll
          for (int j = 0; j < 8; ++j)
            o[j] += cw * win[j + k + 8 - H];
        }
      } else {
        int A0[8], sg[8];
#pragma unroll
        for (int j = 0; j < 8; ++j) {
          const int gx = ox + g * 8 + j;
          int dd = H, rv = 0;
          if (gx < H) dd = gx;
          else if (gx > 1023 - H) { dd = 1023 - gx; rv = 1; }
          A0[j] = dd * T + (rv ? 2 * H : 0);
          sg[j] = rv ? -1 : 1;
        }
#pragma unroll
        for (int j = 0; j < 8; ++j)
          for (int k = 0; k < T; ++k)
            o[j] += sm.Wt[A0[j] + sg[j] * k] * win[j + k + 8 - H];
      }
    }
    __syncthreads();                       // all reads done before any write
    if (val) {
      v4f* d = (v4f*)(sm.buf + i0 * BSTR + g * 8 + 8);
#pragma unroll
      for (int jj = 0; jj < 4; ++jj)
        d[jj] = (v4f){o[2 * jj].x, o[2 * jj].y, o[2 * jj + 1].x, o[2 * jj + 1].y};
    }
  }
  __syncthreads();

  // ---- V pass + fp32 moments: 4 contiguous rows/thread from register window ----
  constexpr float scales[8] = {1.f, 3.f, 9.f, 27.f, 81.f, 243.f, 729.f, 2187.f};
  const float scale = scales[n];
  float sA = 0.f, sB = 0.f, sAA = 0.f, sBB = 0.f, sAB = 0.f;
  {
    const int jt = tid & 31;
    const int iv = tid >> 5;             // 0..7 -> out rows 4iv..4iv+3
    constexpr int C0 = 8 - H, C1 = 11 + H;
    v2f vwin[20];
#pragma unroll
    for (int c = C0; c <= C1; ++c)
      vwin[c] = sm.buf[(4 * iv + c) * BSTR + 8 + jt];
    v2f o[4] = {};
    if (!rowEdge) {
#pragma unroll
      for (int k = 0; k < T; ++k) {
        const float cw = WTAB.w[n][H * T + k];   // compile-time-constant index
#pragma unroll
        for (int rr = 0; rr < 4; ++rr)
          o[rr] += cw * vwin[rr + k + 8 - H];
      }
    } else {
#pragma unroll
      for (int rr = 0; rr < 4; ++rr) {
        const int gy = oy + 4 * iv + rr;
        int dd = H, rv = 0;
        if (gy < H) dd = gy;
        else if (gy > 1023 - H) { dd = 1023 - gy; rv = 1; }
        const int A0 = dd * T + (rv ? 2 * H : 0);
        const int s = rv ? -1 : 1;
        for (int k = 0; k < T; ++k)
          o[rr] += sm.Wt[A0 + s * k] * vwin[rr + k + 8 - H];
      }
    }
#pragma unroll
    for (int rr = 0; rr < 4; ++rr) {
      const float A = scale * o[rr].x;
      const float B = scale * o[rr].y;
      sA += A; sB += B;
      sAA += A * A; sBB += B * B; sAB += A * B;
    }
  }

  // ---- wave shfl reduction -> 4 wave partials -> 5 low-contention atomics ----
  double v[5] = {(double)sA, (double)sB, (double)sAA, (double)sBB, (double)sAB};
#pragma unroll
  for (int off = 32; off > 0; off >>= 1) {
#pragma unroll
    for (int k = 0; k < 5; ++k) v[k] += __shfl_down(v[k], off, 64);
  }
  const int lane = tid & 63, wv = tid >> 6;
  if (lane == 0) {
#pragma unroll
    for (int k = 0; k < 5; ++k) sm.wred[wv * 5 + k] = v[k];
  }
  __syncthreads();
  if (tid == 0) {
#pragma unroll
    for (int k = 0; k < 5; ++k)
      atomicAdd(&accn[k], sm.wred[k] + sm.wred[5 + k] + sm.wred[10 + k] + sm.wred[15 + k]);
  }
}

__global__ __launch_bounds__(256, 8) void ssim_main(const float* __restrict__ xp,
                                                    const float* __restrict__ yp,
                                                    double* __restrict__ acc) {
  __shared__ SharedMem sm;
  const int bid = blockIdx.x;
  const int n = bid & 7;            // sample (== XCD round-robin -> per-XCD L2 affinity)
  const int tile = bid >> 3;        // 0..1023
  const int tc = tile & 31;
  const int tr = tile >> 5;
  const int oy = tr * 32;
  const int ox = tc * 32;
  const int slot = tile & (NSLOT - 1);
  double* accn = acc + (n * NSLOT + slot) * 5;
  switch (n) {
    case 0: body<1>(sm, oy, ox, tr, tc, xp, yp, accn); break;
    case 1: body<2>(sm, oy, ox, tr, tc, xp, yp, accn); break;
    case 2: body<3>(sm, oy, ox, tr, tc, xp, yp, accn); break;
    case 3: body<4>(sm, oy, ox, tr, tc, xp, yp, accn); break;
    case 4: body<5>(sm, oy, ox, tr, tc, xp, yp, accn); break;
    case 5: body<6>(sm, oy, ox, tr, tc, xp, yp, accn); break;
    case 6: body<7>(sm, oy, ox, tr, tc, xp, yp, accn); break;
    default: body<8>(sm, oy, ox, tr, tc, xp, yp, accn); break;
  }
}

__global__ __launch_bounds__(256) void ssim_final(const double* __restrict__ acc,
                                                  float* __restrict__ out) {
  // 256 threads = 8 samples x 32 lanes; lane l sums slots l and l+32.
  __shared__ double terms[8];
  const int tid = threadIdx.x;
  const int s = tid >> 5;
  const int l = tid & 31;
  double v[5];
#pragma unroll
  for (int k = 0; k < 5; ++k)
    v[k] = acc[(s * NSLOT + l) * 5 + k] + acc[(s * NSLOT + l + 32) * 5 + k];
#pragma unroll
  for (int off = 16; off > 0; off >>= 1) {
#pragma unroll
    for (int k = 0; k < 5; ++k) v[k] += __shfl_down(v[k], off, 32);
  }
  if (l == 0) {
    const double C1 = 6.5025;     // (0.01*255)^2
    const double C2 = 58.5225;    // (0.03*255)^2
    const double N = 1048576.0;
    const double mA = v[0] / N, mB = v[1] / N;
    const double varA = (v[2] - N * mA * mA) / (N - 1.0);
    const double varB = (v[3] - N * mB * mB) / (N - 1.0);
    const double cov  = (v[4] - N * mA * mB) / (N - 1.0);
    terms[s] = ((2.0 * mA * mB + C1) * (2.0 * cov + C2)) /
               ((mA * mA + mB * mB + C1) * (varA * varA + varB * varB + C2));
  }
  __syncthreads();
  if (tid == 0) {
    double tot = 0.0;
    for (int i = 0; i < 8; ++i) tot += terms[i];
    out[0] = (float)tot;
  }
}

extern "C" void kernel_launch(void* const* d_in, const int* in_sizes, int n_in,
                              void* d_out, int out_size, void* d_ws, size_t ws_size,
                              hipStream_t stream) {
  const float* x = (const float*)d_in[0];
  const float* y = (const float*)d_in[1];
  double* acc = (double*)d_ws;           // 8*64*5 doubles = 20 KB
  float* out = (float*)d_out;

  ssim_zero<<<1, 256, 0, stream>>>(acc);
  ssim_main<<<8192, 256, 0, stream>>>(x, y, acc);
  ssim_final<<<1, 256, 0, stream>>>(acc, out);
}

// Round 2
// 247.639 us; speedup vs baseline: 1.1125x; 1.1125x over previous
//
#include <hip/hip_runtime.h>

// SSIM-like loss, factored form:
//   term_n uses 3^n * (ZrV)^(n+1) (ZcH)^(n+1) (channel_sum): ONE vertical and ONE
//   horizontal (2h+1)-tap conv with exact edge-clipped weight rows (compile-time
//   __constant__ table). Geometry: 32x32 output tile, 48x48 window, LDS 20,480 B
//   -> 8 blocks/CU. __launch_bounds__(256,5): empirically yields VGPR=64 (the
//   8-wave/SIMD step) with NO scratch spill -- (256,8) forced VGPR=32 and spilled
//   33 MB to scratch (round-1 regression).
//   Accumulation: per-tile private slots + plain stores (no pre-zero kernel, no
//   atomics) when ws_size allows; atomic fallback otherwise.

typedef float v2f __attribute__((ext_vector_type(2)));
typedef float v4f __attribute__((ext_vector_type(4)));

#define BSTR 50     // buf float2 stride (even -> 16B-aligned rows for b128)

#define PC 0.19487473f
#define QC 0.23021731f

// ---- compile-time clipped 1-D weight rows: w[H-1][d*T + k], T = 2H+1,
//      d = dist to edge (0..H-1), d = H = interior row.
struct WtTables { float w[8][153]; };
static constexpr WtTables make_tables() {
  WtTables t{};
  for (int H = 1; H <= 8; ++H) {
    const int T = 2 * H + 1;
    for (int d = 0; d <= H; ++d) {
      float Wd[17] = {};
      for (int k = 0; k < T; ++k) Wd[k] = (k == H) ? 1.f : 0.f;
      const int kmin = H - d;
      for (int m = 0; m < H; ++m) {
        float prev = 0.f;
        for (int k = kmin; k < T; ++k) {
          const float cur = Wd[k];
          const float nxt = (k < T - 1) ? Wd[k + 1] : 0.f;
          Wd[k] = QC * cur + PC * (prev + nxt);
          prev = cur;
        }
      }
      for (int k = 0; k < T; ++k) t.w[H - 1][d * T + k] = Wd[k];
    }
  }
  return t;
}
__constant__ WtTables WTAB = make_tables();

struct SharedMem {
  v2f buf[48 * BSTR];   // 19,200 B  input window -> H output (in place)
  double wred[4 * 5];   //    160 B  per-wave partials
  float Wt[153];        //    612 B  clipped weight rows (edge blocks only)
};                      // 19,972 B -> 20,480 granule -> 8 blocks/CU

__global__ __launch_bounds__(256) void ssim_zero(double* acc) {
  for (int i = threadIdx.x; i < 8 * 64 * 5; i += 256) acc[i] = 0.0;
}

template <int H>
__device__ __forceinline__ void body(SharedMem& sm, int oy, int ox, int tr, int tc,
                                     const float* __restrict__ xp,
                                     const float* __restrict__ yp,
                                     double* __restrict__ accn, int useStore) {
  constexpr int T = 2 * H + 1;
  constexpr int n = H - 1;
  constexpr int R0 = 8 - H, R1 = 39 + H;            // used window rows (0..47)
  const int tid = threadIdx.x;
  const bool rowEdge = (tr == 0) | (tr == 31);
  const bool colEdge = (tc == 0) | (tc == 31);

  // ---- load: window row r <-> gy=oy+r-8, col cell w <-> gx=ox+w-8; zeros outside ----
  {
    constexpr int CC0 = (8 - H) >> 2, CC1 = (39 + H) >> 2;   // used 4-cell chunks
    const size_t base = (size_t)n * 3145728u;
    for (int c = tid; c < 576; c += 256) {        // 48 rows x 12 chunks
      const int row = c / 12;
      const int c4 = c - row * 12;
      if (row < R0 || row > R1 || c4 < CC0 || c4 > CC1) continue;
      const int gy = oy + row - 8;
      const int gx0 = ox + c4 * 4 - 8;
      v4f sx = {0.f, 0.f, 0.f, 0.f}, sy = {0.f, 0.f, 0.f, 0.f};
      if (((unsigned)gy < 1024u) && ((unsigned)gx0 < 1024u)) {
        const size_t off = base + (size_t)gy * 1024u + (unsigned)gx0;
        const v4f* px = (const v4f*)(xp + off);
        const v4f* py = (const v4f*)(yp + off);
        sx = px[0] + px[262144] + px[524288];      // 3-channel sum
        sy = py[0] + py[262144] + py[524288];
      }
      v4f* d = (v4f*)(sm.buf + row * BSTR + c4 * 4);
      d[0] = (v4f){sx.x, sy.x, sx.y, sy.y};
      d[1] = (v4f){sx.z, sy.z, sx.w, sy.w};
    }
  }
  // ---- edge blocks stage the weight table in LDS (dynamic per-lane indexing) ----
  if (rowEdge | colEdge) {
    for (int i = tid; i < (H + 1) * T; i += 256) sm.Wt[i] = WTAB.w[n][i];
  }
  __syncthreads();

  // ---- H pass IN PLACE: wave g owns col-group g (8 out cols), lane = window row ----
  {
    const int g = tid >> 6;              // col-group 0..3 (wave-uniform)
    const int i0 = tid & 63;             // window row
    constexpr int I0 = (8 - H) >> 1, I1 = (15 + H) >> 1;   // b128 read range
    const bool val = (i0 >= R0) & (i0 <= R1);
    v2f o[8] = {};
    if (val) {
      const v4f* s4 = (const v4f*)(sm.buf + i0 * BSTR + g * 8);
      v2f win[24];
#pragma unroll
      for (int i = I0; i <= I1; ++i) {
        const v4f t = s4[i];
        win[2 * i] = (v2f){t.x, t.y};
        win[2 * i + 1] = (v2f){t.z, t.w};
      }
      if (!colEdge) {
#pragma unroll
        for (int k = 0; k < T; ++k) {
          const float cw = WTAB.w[n][H * T + k];   // compile-time-constant index
#pragma unroll
          for (int j = 0; j < 8; ++j)
            o[j] += cw * win[j + k + 8 - H];
        }
      } else {
        int A0[8], sg[8];
#pragma unroll
        for (int j = 0; j < 8; ++j) {
          const int gx = ox + g * 8 + j;
          int dd = H, rv = 0;
          if (gx < H) dd = gx;
          else if (gx > 1023 - H) { dd = 1023 - gx; rv = 1; }
          A0[j] = dd * T + (rv ? 2 * H : 0);
          sg[j] = rv ? -1 : 1;
        }
#pragma unroll
        for (int j = 0; j < 8; ++j)
          for (int k = 0; k < T; ++k)
            o[j] += sm.Wt[A0[j] + sg[j] * k] * win[j + k + 8 - H];
      }
    }
    __syncthreads();                       // all reads done before any write
    if (val) {
      v4f* d = (v4f*)(sm.buf + i0 * BSTR + g * 8 + 8);
#pragma unroll
      for (int jj = 0; jj < 4; ++jj)
        d[jj] = (v4f){o[2 * jj].x, o[2 * jj].y, o[2 * jj + 1].x, o[2 * jj + 1].y};
    }
  }
  __syncthreads();

  // ---- V pass + fp32 moments: 4 contiguous rows/thread from register window ----
  constexpr float scales[8] = {1.f, 3.f, 9.f, 27.f, 81.f, 243.f, 729.f, 2187.f};
  const float scale = scales[n];
  float sA = 0.f, sB = 0.f, sAA = 0.f, sBB = 0.f, sAB = 0.f;
  {
    const int jt = tid & 31;
    const int iv = tid >> 5;             // 0..7 -> out rows 4iv..4iv+3
    constexpr int C0 = 8 - H, C1 = 11 + H;
    v2f vwin[20];
#pragma unroll
    for (int c = C0; c <= C1; ++c)
      vwin[c] = sm.buf[(4 * iv + c) * BSTR + 8 + jt];
    v2f o[4] = {};
    if (!rowEdge) {
#pragma unroll
      for (int k = 0; k < T; ++k) {
        const float cw = WTAB.w[n][H * T + k];   // compile-time-constant index
#pragma unroll
        for (int rr = 0; rr < 4; ++rr)
          o[rr] += cw * vwin[rr + k + 8 - H];
      }
    } else {
#pragma unroll
      for (int rr = 0; rr < 4; ++rr) {
        const int gy = oy + 4 * iv + rr;
        int dd = H, rv = 0;
        if (gy < H) dd = gy;
        else if (gy > 1023 - H) { dd = 1023 - gy; rv = 1; }
        const int A0 = dd * T + (rv ? 2 * H : 0);
        const int s = rv ? -1 : 1;
        for (int k = 0; k < T; ++k)
          o[rr] += sm.Wt[A0 + s * k] * vwin[rr + k + 8 - H];
      }
    }
#pragma unroll
    for (int rr = 0; rr < 4; ++rr) {
      const float A = scale * o[rr].x;
      const float B = scale * o[rr].y;
      sA += A; sB += B;
      sAA += A * A; sBB += B * B; sAB += A * B;
    }
  }

  // ---- wave shfl reduction -> 4 wave partials -> 5 stores (or atomics fallback) ----
  double v[5] = {(double)sA, (double)sB, (double)sAA, (double)sBB, (double)sAB};
#pragma unroll
  for (int off = 32; off > 0; off >>= 1) {
#pragma unroll
    for (int k = 0; k < 5; ++k) v[k] += __shfl_down(v[k], off, 64);
  }
  const int lane = tid & 63, wv = tid >> 6;
  if (lane == 0) {
#pragma unroll
    for (int k = 0; k < 5; ++k) sm.wred[wv * 5 + k] = v[k];
  }
  __syncthreads();
  if (tid == 0) {
    if (useStore) {
#pragma unroll
      for (int k = 0; k < 5; ++k)
        accn[k] = sm.wred[k] + sm.wred[5 + k] + sm.wred[10 + k] + sm.wred[15 + k];
    } else {
#pragma unroll
      for (int k = 0; k < 5; ++k)
        atomicAdd(&accn[k], sm.wred[k] + sm.wred[5 + k] + sm.wred[10 + k] + sm.wred[15 + k]);
    }
  }
}

__global__ __launch_bounds__(256, 5) void ssim_main(const float* __restrict__ xp,
                                                    const float* __restrict__ yp,
                                                    double* __restrict__ acc,
                                                    int nslot, int useStore) {
  __shared__ SharedMem sm;
  const int bid = blockIdx.x;
  const int n = bid & 7;            // sample (== XCD round-robin -> per-XCD L2 affinity)
  const int tile = bid >> 3;        // 0..1023
  const int tc = tile & 31;
  const int tr = tile >> 5;
  const int oy = tr * 32;
  const int ox = tc * 32;
  const int slot = tile & (nslot - 1);
  double* accn = acc + (n * nslot + slot) * 5;
  switch (n) {
    case 0: body<1>(sm, oy, ox, tr, tc, xp, yp, accn, useStore); break;
    case 1: body<2>(sm, oy, ox, tr, tc, xp, yp, accn, useStore); break;
    case 2: body<3>(sm, oy, ox, tr, tc, xp, yp, accn, useStore); break;
    case 3: body<4>(sm, oy, ox, tr, tc, xp, yp, accn, useStore); break;
    case 4: body<5>(sm, oy, ox, tr, tc, xp, yp, accn, useStore); break;
    case 5: body<6>(sm, oy, ox, tr, tc, xp, yp, accn, useStore); break;
    case 6: body<7>(sm, oy, ox, tr, tc, xp, yp, accn, useStore); break;
    default: body<8>(sm, oy, ox, tr, tc, xp, yp, accn, useStore); break;
  }
}

__global__ __launch_bounds__(256) void ssim_final(const double* __restrict__ acc,
                                                  float* __restrict__ out, int nslot) {
  // 256 threads = 8 samples x 32 lanes; lane l sums slots l, l+32, ...
  __shared__ double terms[8];
  const int tid = threadIdx.x;
  const int s = tid >> 5;
  const int l = tid & 31;
  double v[5] = {0.0, 0.0, 0.0, 0.0, 0.0};
  for (int slot = l; slot < nslot; slot += 32) {
    const double* p = acc + (size_t)(s * nslot + slot) * 5;
#pragma unroll
    for (int k = 0; k < 5; ++k) v[k] += p[k];
  }
#pragma unroll
  for (int off = 16; off > 0; off >>= 1) {
#pragma unroll
    for (int k = 0; k < 5; ++k) v[k] += __shfl_down(v[k], off, 32);
  }
  if (l == 0) {
    const double C1 = 6.5025;     // (0.01*255)^2
    const double C2 = 58.5225;    // (0.03*255)^2
    const double N = 1048576.0;
    const double mA = v[0] / N, mB = v[1] / N;
    const double varA = (v[2] - N * mA * mA) / (N - 1.0);
    const double varB = (v[3] - N * mB * mB) / (N - 1.0);
    const double cov  = (v[4] - N * mA * mB) / (N - 1.0);
    terms[s] = ((2.0 * mA * mB + C1) * (2.0 * cov + C2)) /
               ((mA * mA + mB * mB + C1) * (varA * varA + varB * varB + C2));
  }
  __syncthreads();
  if (tid == 0) {
    double tot = 0.0;
    for (int i = 0; i < 8; ++i) tot += terms[i];
    out[0] = (float)tot;
  }
}

extern "C" void kernel_launch(void* const* d_in, const int* in_sizes, int n_in,
                              void* d_out, int out_size, void* d_ws, size_t ws_size,
                              hipStream_t stream) {
  const float* x = (const float*)d_in[0];
  const float* y = (const float*)d_in[1];
  double* acc = (double*)d_ws;
  float* out = (float*)d_out;

  // Per-tile private slots (no zeroing, no atomics) if the workspace allows:
  const size_t need = (size_t)8 * 1024 * 5 * sizeof(double);   // 320 KB
  const int bigws = ws_size >= need;
  const int nslot = bigws ? 1024 : 64;

  if (!bigws) ssim_zero<<<1, 256, 0, stream>>>(acc);
  ssim_main<<<8192, 256, 0, stream>>>(x, y, acc, nslot, bigws);
  ssim_final<<<1, 256, 0, stream>>>(acc, out, nslot);
}

// Round 3
// 246.856 us; speedup vs baseline: 1.1160x; 1.0032x over previous
//
#include <hip/hip_runtime.h>

// SSIM-like loss, factored form:
//   term_n uses 3^n * (ZrV)^(n+1) (ZcH)^(n+1) (channel_sum): ONE vertical and ONE
//   horizontal (2h+1)-tap conv with exact edge-clipped weight rows (compile-time
//   __constant__ table). Geometry: 32x32 output tile, 48x48 window, LDS 20,480 B
//   -> 8 blocks/CU. __launch_bounds__(256,5) -> VGPR<=64, no spill ((256,8) spilled).
//   R3 change: SAMPLE-MAJOR block order (n = bid>>10, was bid&7). With bid&7 the
//   ~8 co-resident blocks per CU ran 8 DIFFERENT template bodies -> I-cache thrash
//   theory for the observed all-pipes-idle stall (VALU 19%, LDS 18%, HBM 13%).
//   Sample-major keeps co-resident blocks on <=2-3 variants.
//   Accumulation: per-tile private slots + plain stores (no zero pass, no atomics)
//   when ws_size allows; atomic fallback otherwise. Final pass: 1024 threads.

typedef float v2f __attribute__((ext_vector_type(2)));
typedef float v4f __attribute__((ext_vector_type(4)));

#define BSTR 50     // buf float2 stride (even -> 16B-aligned rows for b128)

#define PC 0.19487473f
#define QC 0.23021731f

// ---- compile-time clipped 1-D weight rows: w[H-1][d*T + k], T = 2H+1,
//      d = dist to edge (0..H-1), d = H = interior row.
struct WtTables { float w[8][153]; };
static constexpr WtTables make_tables() {
  WtTables t{};
  for (int H = 1; H <= 8; ++H) {
    const int T = 2 * H + 1;
    for (int d = 0; d <= H; ++d) {
      float Wd[17] = {};
      for (int k = 0; k < T; ++k) Wd[k] = (k == H) ? 1.f : 0.f;
      const int kmin = H - d;
      for (int m = 0; m < H; ++m) {
        float prev = 0.f;
        for (int k = kmin; k < T; ++k) {
          const float cur = Wd[k];
          const float nxt = (k < T - 1) ? Wd[k + 1] : 0.f;
          Wd[k] = QC * cur + PC * (prev + nxt);
          prev = cur;
        }
      }
      for (int k = 0; k < T; ++k) t.w[H - 1][d * T + k] = Wd[k];
    }
  }
  return t;
}
__constant__ WtTables WTAB = make_tables();

struct SharedMem {
  v2f buf[48 * BSTR];   // 19,200 B  input window -> H output (in place)
  double wred[4 * 5];   //    160 B  per-wave partials
  float Wt[153];        //    612 B  clipped weight rows (edge blocks only)
};                      // 19,972 B -> 20,480 granule -> 8 blocks/CU

__global__ __launch_bounds__(256) void ssim_zero(double* acc) {
  for (int i = threadIdx.x; i < 8 * 64 * 5; i += 256) acc[i] = 0.0;
}

template <int H>
__device__ __forceinline__ void body(SharedMem& sm, int oy, int ox, int tr, int tc,
                                     const float* __restrict__ xp,
                                     const float* __restrict__ yp,
                                     double* __restrict__ accn, int useStore) {
  constexpr int T = 2 * H + 1;
  constexpr int n = H - 1;
  constexpr int R0 = 8 - H, R1 = 39 + H;            // used window rows (0..47)
  const int tid = threadIdx.x;
  const bool rowEdge = (tr == 0) | (tr == 31);
  const bool colEdge = (tc == 0) | (tc == 31);

  // ---- load: window row r <-> gy=oy+r-8, col cell w <-> gx=ox+w-8; zeros outside.
  //      Straight-line 3 chunks (576 = 48 rows x 12 chunks) so loads issue back-to-back.
  {
    constexpr int CC0 = (8 - H) >> 2, CC1 = (39 + H) >> 2;   // used 4-cell chunks
    const size_t base = (size_t)n * 3145728u;
    auto doChunk = [&](int c) {
      const int row = c / 12;
      const int c4 = c - row * 12;
      if (row < R0 || row > R1 || c4 < CC0 || c4 > CC1) return;
      const int gy = oy + row - 8;
      const int gx0 = ox + c4 * 4 - 8;
      v4f sx = {0.f, 0.f, 0.f, 0.f}, sy = {0.f, 0.f, 0.f, 0.f};
      if (((unsigned)gy < 1024u) && ((unsigned)gx0 < 1024u)) {
        const size_t off = base + (size_t)gy * 1024u + (unsigned)gx0;
        const v4f* px = (const v4f*)(xp + off);
        const v4f* py = (const v4f*)(yp + off);
        sx = px[0] + px[262144] + px[524288];      // 3-channel sum
        sy = py[0] + py[262144] + py[524288];
      }
      v4f* d = (v4f*)(sm.buf + row * BSTR + c4 * 4);
      d[0] = (v4f){sx.x, sy.x, sx.y, sy.y};
      d[1] = (v4f){sx.z, sy.z, sx.w, sy.w};
    };
    doChunk(tid);
    doChunk(tid + 256);
    if (tid < 64) doChunk(tid + 512);
  }
  // ---- edge blocks stage the weight table in LDS (dynamic per-lane indexing) ----
  if (rowEdge | colEdge) {
    for (int i = tid; i < (H + 1) * T; i += 256) sm.Wt[i] = WTAB.w[n][i];
  }
  __syncthreads();

  // ---- H pass IN PLACE: wave g owns col-group g (8 out cols), lane = window row ----
  {
    const int g = tid >> 6;              // col-group 0..3 (wave-uniform)
    const int i0 = tid & 63;             // window row
    constexpr int I0 = (8 - H) >> 1, I1 = (15 + H) >> 1;   // b128 read range
    const bool val = (i0 >= R0) & (i0 <= R1);
    v2f o[8] = {};
    if (val) {
      const v4f* s4 = (const v4f*)(sm.buf + i0 * BSTR + g * 8);
      v2f win[24];
#pragma unroll
      for (int i = I0; i <= I1; ++i) {
        const v4f t = s4[i];
        win[2 * i] = (v2f){t.x, t.y};
        win[2 * i + 1] = (v2f){t.z, t.w};
      }
      if (!colEdge) {
#pragma unroll
        for (int k = 0; k < T; ++k) {
          const float cw = WTAB.w[n][H * T + k];   // compile-time-constant index
#pragma unroll
          for (int j = 0; j < 8; ++j)
            o[j] += cw * win[j + k + 8 - H];
        }
      } else {
        int A0[8], sg[8];
#pragma unroll
        for (int j = 0; j < 8; ++j) {
          const int gx = ox + g * 8 + j;
          int dd = H, rv = 0;
          if (gx < H) dd = gx;
          else if (gx > 1023 - H) { dd = 1023 - gx; rv = 1; }
          A0[j] = dd * T + (rv ? 2 * H : 0);
          sg[j] = rv ? -1 : 1;
        }
#pragma unroll
        for (int j = 0; j < 8; ++j)
          for (int k = 0; k < T; ++k)
            o[j] += sm.Wt[A0[j] + sg[j] * k] * win[j + k + 8 - H];
      }
    }
    __syncthreads();                       // all reads done before any write
    if (val) {
      v4f* d = (v4f*)(sm.buf + i0 * BSTR + g * 8 + 8);
#pragma unroll
      for (int jj = 0; jj < 4; ++jj)
        d[jj] = (v4f){o[2 * jj].x, o[2 * jj].y, o[2 * jj + 1].x, o[2 * jj + 1].y};
    }
  }
  __syncthreads();

  // ---- V pass + fp32 moments: 4 contiguous rows/thread from register window ----
  constexpr float scales[8] = {1.f, 3.f, 9.f, 27.f, 81.f, 243.f, 729.f, 2187.f};
  const float scale = scales[n];
  float sA = 0.f, sB = 0.f, sAA = 0.f, sBB = 0.f, sAB = 0.f;
  {
    const int jt = tid & 31;
    const int iv = tid >> 5;             // 0..7 -> out rows 4iv..4iv+3
    constexpr int C0 = 8 - H, C1 = 11 + H;
    v2f vwin[20];
#pragma unroll
    for (int c = C0; c <= C1; ++c)
      vwin[c] = sm.buf[(4 * iv + c) * BSTR + 8 + jt];
    v2f o[4] = {};
    if (!rowEdge) {
#pragma unroll
      for (int k = 0; k < T; ++k) {
        const float cw = WTAB.w[n][H * T + k];   // compile-time-constant index
#pragma unroll
        for (int rr = 0; rr < 4; ++rr)
          o[rr] += cw * vwin[rr + k + 8 - H];
      }
    } else {
#pragma unroll
      for (int rr = 0; rr < 4; ++rr) {
        const int gy = oy + 4 * iv + rr;
        int dd = H, rv = 0;
        if (gy < H) dd = gy;
        else if (gy > 1023 - H) { dd = 1023 - gy; rv = 1; }
        const int A0 = dd * T + (rv ? 2 * H : 0);
        const int s = rv ? -1 : 1;
        for (int k = 0; k < T; ++k)
          o[rr] += sm.Wt[A0 + s * k] * vwin[rr + k + 8 - H];
      }
    }
#pragma unroll
    for (int rr = 0; rr < 4; ++rr) {
      const float A = scale * o[rr].x;
      const float B = scale * o[rr].y;
      sA += A; sB += B;
      sAA += A * A; sBB += B * B; sAB += A * B;
    }
  }

  // ---- wave shfl reduction -> 4 wave partials -> 5 stores (or atomics fallback) ----
  double v[5] = {(double)sA, (double)sB, (double)sAA, (double)sBB, (double)sAB};
#pragma unroll
  for (int off = 32; off > 0; off >>= 1) {
#pragma unroll
    for (int k = 0; k < 5; ++k) v[k] += __shfl_down(v[k], off, 64);
  }
  const int lane = tid & 63, wv = tid >> 6;
  if (lane == 0) {
#pragma unroll
    for (int k = 0; k < 5; ++k) sm.wred[wv * 5 + k] = v[k];
  }
  __syncthreads();
  if (tid == 0) {
    if (useStore) {
#pragma unroll
      for (int k = 0; k < 5; ++k)
        accn[k] = sm.wred[k] + sm.wred[5 + k] + sm.wred[10 + k] + sm.wred[15 + k];
    } else {
#pragma unroll
      for (int k = 0; k < 5; ++k)
        atomicAdd(&accn[k], sm.wred[k] + sm.wred[5 + k] + sm.wred[10 + k] + sm.wred[15 + k]);
    }
  }
}

__global__ __launch_bounds__(256, 5) void ssim_main(const float* __restrict__ xp,
                                                    const float* __restrict__ yp,
                                                    double* __restrict__ acc,
                                                    int nslot, int useStore) {
  __shared__ SharedMem sm;
  const int bid = blockIdx.x;
  const int n = bid >> 10;          // SAMPLE-MAJOR: co-resident blocks share body<H>
  const int tile = bid & 1023;
  const int tc = tile & 31;
  const int tr = tile >> 5;
  const int oy = tr * 32;
  const int ox = tc * 32;
  const int slot = tile & (nslot - 1);
  double* accn = acc + (n * nslot + slot) * 5;
  switch (n) {
    case 0: body<1>(sm, oy, ox, tr, tc, xp, yp, accn, useStore); break;
    case 1: body<2>(sm, oy, ox, tr, tc, xp, yp, accn, useStore); break;
    case 2: body<3>(sm, oy, ox, tr, tc, xp, yp, accn, useStore); break;
    case 3: body<4>(sm, oy, ox, tr, tc, xp, yp, accn, useStore); break;
    case 4: body<5>(sm, oy, ox, tr, tc, xp, yp, accn, useStore); break;
    case 5: body<6>(sm, oy, ox, tr, tc, xp, yp, accn, useStore); break;
    case 6: body<7>(sm, oy, ox, tr, tc, xp, yp, accn, useStore); break;
    default: body<8>(sm, oy, ox, tr, tc, xp, yp, accn, useStore); break;
  }
}

__global__ __launch_bounds__(1024) void ssim_final(const double* __restrict__ acc,
                                                   float* __restrict__ out, int nslot) {
  // 1024 threads = 8 samples x 128 lanes; lane l sums slots l, l+128, ...
  __shared__ double wp[16][5];
  __shared__ double terms[8];
  const int tid = threadIdx.x;
  const int s = tid >> 7;
  const int l = tid & 127;
  double v[5] = {0.0, 0.0, 0.0, 0.0, 0.0};
  for (int slot = l; slot < nslot; slot += 128) {
    const double* p = acc + (size_t)(s * nslot + slot) * 5;
#pragma unroll
    for (int k = 0; k < 5; ++k) v[k] += p[k];
  }
#pragma unroll
  for (int off = 32; off > 0; off >>= 1) {
#pragma unroll
    for (int k = 0; k < 5; ++k) v[k] += __shfl_down(v[k], off, 64);
  }
  if ((tid & 63) == 0) {
#pragma unroll
    for (int k = 0; k < 5; ++k) wp[tid >> 6][k] = v[k];
  }
  __syncthreads();
  if (tid < 8) {
    double u[5];
#pragma unroll
    for (int k = 0; k < 5; ++k) u[k] = wp[2 * tid][k] + wp[2 * tid + 1][k];
    const double C1 = 6.5025;     // (0.01*255)^2
    const double C2 = 58.5225;    // (0.03*255)^2
    const double N = 1048576.0;
    const double mA = u[0] / N, mB = u[1] / N;
    const double varA = (u[2] - N * mA * mA) / (N - 1.0);
    const double varB = (u[3] - N * mB * mB) / (N - 1.0);
    const double cov  = (u[4] - N * mA * mB) / (N - 1.0);
    terms[tid] = ((2.0 * mA * mB + C1) * (2.0 * cov + C2)) /
                 ((mA * mA + mB * mB + C1) * (varA * varA + varB * varB + C2));
  }
  __syncthreads();
  if (tid == 0) {
    double tot = 0.0;
    for (int i = 0; i < 8; ++i) tot += terms[i];
    out[0] = (float)tot;
  }
}

extern "C" void kernel_launch(void* const* d_in, const int* in_sizes, int n_in,
                              void* d_out, int out_size, void* d_ws, size_t ws_size,
                              hipStream_t stream) {
  const float* x = (const float*)d_in[0];
  const float* y = (const float*)d_in[1];
  double* acc = (double*)d_ws;
  float* out = (float*)d_out;

  // Per-tile private slots (no zeroing, no atomics) if the workspace allows:
  const size_t need = (size_t)8 * 1024 * 5 * sizeof(double);   // 320 KB
  const int bigws = ws_size >= need;
  const int nslot = bigws ? 1024 : 64;

  if (!bigws) ssim_zero<<<1, 256, 0, stream>>>(acc);
  ssim_main<<<8192, 256, 0, stream>>>(x, y, acc, nslot, bigws);
  ssim_final<<<1, 1024, 0, stream>>>(acc, out, nslot);
}

// Round 4
// 236.326 us; speedup vs baseline: 1.1657x; 1.0446x over previous
//
#include <hip/hip_runtime.h>

// SSIM-like loss, factored form:
//   term_n uses 3^n * (ZrV)^(n+1) (ZcH)^(n+1) (channel_sum): ONE vertical and ONE
//   horizontal (2h+1)-tap conv with exact edge-clipped weight rows (compile-time
//   __constant__ table). Geometry: 32x32 output tile, 48x48 window, LDS 20,480 B.
//   R4: (1) REVERT to interleaved n=bid&7 (XCD<->sample L2 affinity: sample-major
//   tripled FETCH 98->316 MB, +9 us). (2) MLP-batched load phase: 3 channel passes
//   with LDS accumulate; 8 v4f loads in flight before first wait (was 6 loads ->
//   wait -> next chunk: 3 serialized round-trips). Model: BW/wave was constant
//   (~0.53 B/cyc/wave) across rounds -> latency-bound, per-wave MLP is the lever.
//   __launch_bounds__(256,5): empirically no spill ((256,8) spilled 33 MB in R1).

typedef float v2f __attribute__((ext_vector_type(2)));
typedef float v4f __attribute__((ext_vector_type(4)));

#define BSTR 50     // buf float2 stride (even -> 16B-aligned rows for b128)

#define PC 0.19487473f
#define QC 0.23021731f

// ---- compile-time clipped 1-D weight rows: w[H-1][d*T + k], T = 2H+1,
//      d = dist to edge (0..H-1), d = H = interior row.
struct WtTables { float w[8][153]; };
static constexpr WtTables make_tables() {
  WtTables t{};
  for (int H = 1; H <= 8; ++H) {
    const int T = 2 * H + 1;
    for (int d = 0; d <= H; ++d) {
      float Wd[17] = {};
      for (int k = 0; k < T; ++k) Wd[k] = (k == H) ? 1.f : 0.f;
      const int kmin = H - d;
      for (int m = 0; m < H; ++m) {
        float prev = 0.f;
        for (int k = kmin; k < T; ++k) {
          const float cur = Wd[k];
          const float nxt = (k < T - 1) ? Wd[k + 1] : 0.f;
          Wd[k] = QC * cur + PC * (prev + nxt);
          prev = cur;
        }
      }
      for (int k = 0; k < T; ++k) t.w[H - 1][d * T + k] = Wd[k];
    }
  }
  return t;
}
__constant__ WtTables WTAB = make_tables();

struct SharedMem {
  v2f buf[48 * BSTR];   // 19,200 B  input window -> H output (in place)
  double wred[4 * 5];   //    160 B  per-wave partials
  float Wt[153];        //    612 B  clipped weight rows (edge blocks only)
};                      // 19,972 B -> 20,480 granule -> 8 blocks/CU

__global__ __launch_bounds__(256) void ssim_zero(double* acc) {
  for (int i = threadIdx.x; i < 8 * 64 * 5; i += 256) acc[i] = 0.0;
}

template <int H>
__device__ __forceinline__ void body(SharedMem& sm, int oy, int ox, int tr, int tc,
                                     const float* __restrict__ xp,
                                     const float* __restrict__ yp,
                                     double* __restrict__ accn, int useStore) {
  constexpr int T = 2 * H + 1;
  constexpr int n = H - 1;
  constexpr int R0 = 8 - H, R1 = 39 + H;            // used window rows (0..47)
  const int tid = threadIdx.x;
  const bool rowEdge = (tr == 0) | (tr == 31);
  const bool colEdge = (tc == 0) | (tc == 31);

  // ---- load phase: MLP-batched. Cells A=tid, B=tid+256 (of 576 = 48 rows x 12
  //      4-float chunks); 3 channel passes accumulate into LDS (thread-private
  //      cells, same-wave DS ops are in-order -> no barrier needed between passes).
  //      Pass0+pass1 loads (8 v4f) issue before the first vmcnt wait; pass2 issues
  //      while pass1 is in flight. Cell C (tid<64) serial afterward.
  {
    constexpr int CC0 = (8 - H) >> 2, CC1 = (39 + H) >> 2;   // used 4-cell chunks
    const size_t base = (size_t)n * 3145728u;
    const int cA = tid, cB = tid + 256;
    const int rowA = cA / 12, c4A = cA - rowA * 12;
    const int rowB = cB / 12, c4B = cB - rowB * 12;
    const int gyA = oy + rowA - 8, gxA = ox + c4A * 4 - 8;
    const int gyB = oy + rowB - 8, gxB = ox + c4B * 4 - 8;
    const bool uA = (rowA >= R0) & (rowA <= R1) & (c4A >= CC0) & (c4A <= CC1);
    const bool uB = (rowB >= R0) & (rowB <= R1) & (c4B >= CC0) & (c4B <= CC1);
    const bool okA = uA & (((unsigned)gyA < 1024u) & ((unsigned)gxA < 1024u));
    const bool okB = uB & (((unsigned)gyB < 1024u) & ((unsigned)gxB < 1024u));
    const size_t offA = okA ? base + (size_t)gyA * 1024u + (unsigned)gxA : base;
    const size_t offB = okB ? base + (size_t)gyB * 1024u + (unsigned)gxB : base;
    const v4f* pxA = (const v4f*)(xp + offA);
    const v4f* pyA = (const v4f*)(yp + offA);
    const v4f* pxB = (const v4f*)(xp + offB);
    const v4f* pyB = (const v4f*)(yp + offB);
    v4f* dA = (v4f*)(sm.buf + rowA * BSTR + c4A * 4);
    v4f* dB = (v4f*)(sm.buf + rowB * BSTR + c4B * 4);

    v4f xa0, ya0, xb0, yb0, xa1, ya1, xb1, yb1;
    if (okA) { xa0 = pxA[0]; ya0 = pyA[0]; }                   // ch0 issue
    if (okB) { xb0 = pxB[0]; yb0 = pyB[0]; }
    if (okA) { xa1 = pxA[262144]; ya1 = pyA[262144]; }         // ch1 issue
    if (okB) { xb1 = pxB[262144]; yb1 = pyB[262144]; }

    // pass 0 consume (waits ch0 only; ch1 stays in flight)
    if (uA) {
      v4f sx = {0.f, 0.f, 0.f, 0.f}, sy = {0.f, 0.f, 0.f, 0.f};
      if (okA) { sx = xa0; sy = ya0; }
      dA[0] = (v4f){sx.x, sy.x, sx.y, sy.y};
      dA[1] = (v4f){sx.z, sy.z, sx.w, sy.w};
    }
    if (uB) {
      v4f sx = {0.f, 0.f, 0.f, 0.f}, sy = {0.f, 0.f, 0.f, 0.f};
      if (okB) { sx = xb0; sy = yb0; }
      dB[0] = (v4f){sx.x, sy.x, sx.y, sy.y};
      dB[1] = (v4f){sx.z, sy.z, sx.w, sy.w};
    }
    // ch2 issue (while ch1 in flight)
    v4f xa2, ya2, xb2, yb2;
    if (okA) { xa2 = pxA[524288]; ya2 = pyA[524288]; }
    if (okB) { xb2 = pxB[524288]; yb2 = pyB[524288]; }
    // pass 1 consume (LDS accumulate)
    if (okA) {
      dA[0] += (v4f){xa1.x, ya1.x, xa1.y, ya1.y};
      dA[1] += (v4f){xa1.z, ya1.z, xa1.w, ya1.w};
    }
    if (okB) {
      dB[0] += (v4f){xb1.x, yb1.x, xb1.y, yb1.y};
      dB[1] += (v4f){xb1.z, yb1.z, xb1.w, yb1.w};
    }
    // pass 2 consume
    if (okA) {
      dA[0] += (v4f){xa2.x, ya2.x, xa2.y, ya2.y};
      dA[1] += (v4f){xa2.z, ya2.z, xa2.w, ya2.w};
    }
    if (okB) {
      dB[0] += (v4f){xb2.x, yb2.x, xb2.y, yb2.y};
      dB[1] += (v4f){xb2.z, yb2.z, xb2.w, yb2.w};
    }
    // cell C: chunks 512..575 (rows 42..47), one wave, serial old-style
    if (tid < 64) {
      const int cC = tid + 512;
      const int rowC = cC / 12, c4C = cC - rowC * 12;
      if (rowC >= R0 && rowC <= R1 && c4C >= CC0 && c4C <= CC1) {
        const int gyC = oy + rowC - 8, gxC = ox + c4C * 4 - 8;
        v4f sx = {0.f, 0.f, 0.f, 0.f}, sy = {0.f, 0.f, 0.f, 0.f};
        if (((unsigned)gyC < 1024u) && ((unsigned)gxC < 1024u)) {
          const size_t off = base + (size_t)gyC * 1024u + (unsigned)gxC;
          const v4f* px = (const v4f*)(xp + off);
          const v4f* py = (const v4f*)(yp + off);
          sx = px[0] + px[262144] + px[524288];
          sy = py[0] + py[262144] + py[524288];
        }
        v4f* d = (v4f*)(sm.buf + rowC * BSTR + c4C * 4);
        d[0] = (v4f){sx.x, sy.x, sx.y, sy.y};
        d[1] = (v4f){sx.z, sy.z, sx.w, sy.w};
      }
    }
  }
  // ---- edge blocks stage the weight table in LDS (dynamic per-lane indexing) ----
  if (rowEdge | colEdge) {
    for (int i = tid; i < (H + 1) * T; i += 256) sm.Wt[i] = WTAB.w[n][i];
  }
  __syncthreads();

  // ---- H pass IN PLACE: wave g owns col-group g (8 out cols), lane = window row ----
  {
    const int g = tid >> 6;              // col-group 0..3 (wave-uniform)
    const int i0 = tid & 63;             // window row
    constexpr int I0 = (8 - H) >> 1, I1 = (15 + H) >> 1;   // b128 read range
    const bool val = (i0 >= R0) & (i0 <= R1);
    v2f o[8] = {};
    if (val) {
      const v4f* s4 = (const v4f*)(sm.buf + i0 * BSTR + g * 8);
      v2f win[24];
#pragma unroll
      for (int i = I0; i <= I1; ++i) {
        const v4f t = s4[i];
        win[2 * i] = (v2f){t.x, t.y};
        win[2 * i + 1] = (v2f){t.z, t.w};
      }
      if (!colEdge) {
#pragma unroll
        for (int k = 0; k < T; ++k) {
          const float cw = WTAB.w[n][H * T + k];   // compile-time-constant index
#pragma unroll
          for (int j = 0; j < 8; ++j)
            o[j] += cw * win[j + k + 8 - H];
        }
      } else {
        int A0[8], sg[8];
#pragma unroll
        for (int j = 0; j < 8; ++j) {
          const int gx = ox + g * 8 + j;
          int dd = H, rv = 0;
          if (gx < H) dd = gx;
          else if (gx > 1023 - H) { dd = 1023 - gx; rv = 1; }
          A0[j] = dd * T + (rv ? 2 * H : 0);
          sg[j] = rv ? -1 : 1;
        }
#pragma unroll
        for (int j = 0; j < 8; ++j)
          for (int k = 0; k < T; ++k)
            o[j] += sm.Wt[A0[j] + sg[j] * k] * win[j + k + 8 - H];
      }
    }
    __syncthreads();                       // all reads done before any write
    if (val) {
      v4f* d = (v4f*)(sm.buf + i0 * BSTR + g * 8 + 8);
#pragma unroll
      for (int jj = 0; jj < 4; ++jj)
        d[jj] = (v4f){o[2 * jj].x, o[2 * jj].y, o[2 * jj + 1].x, o[2 * jj + 1].y};
    }
  }
  __syncthreads();

  // ---- V pass + fp32 moments: 4 contiguous rows/thread from register window ----
  constexpr float scales[8] = {1.f, 3.f, 9.f, 27.f, 81.f, 243.f, 729.f, 2187.f};
  const float scale = scales[n];
  float sA = 0.f, sB = 0.f, sAA = 0.f, sBB = 0.f, sAB = 0.f;
  {
    const int jt = tid & 31;
    const int iv = tid >> 5;             // 0..7 -> out rows 4iv..4iv+3
    constexpr int C0 = 8 - H, C1 = 11 + H;
    v2f vwin[20];
#pragma unroll
    for (int c = C0; c <= C1; ++c)
      vwin[c] = sm.buf[(4 * iv + c) * BSTR + 8 + jt];
    v2f o[4] = {};
    if (!rowEdge) {
#pragma unroll
      for (int k = 0; k < T; ++k) {
        const float cw = WTAB.w[n][H * T + k];   // compile-time-constant index
#pragma unroll
        for (int rr = 0; rr < 4; ++rr)
          o[rr] += cw * vwin[rr + k + 8 - H];
      }
    } else {
#pragma unroll
      for (int rr = 0; rr < 4; ++rr) {
        const int gy = oy + 4 * iv + rr;
        int dd = H, rv = 0;
        if (gy < H) dd = gy;
        else if (gy > 1023 - H) { dd = 1023 - gy; rv = 1; }
        const int A0 = dd * T + (rv ? 2 * H : 0);
        const int s = rv ? -1 : 1;
        for (int k = 0; k < T; ++k)
          o[rr] += sm.Wt[A0 + s * k] * vwin[rr + k + 8 - H];
      }
    }
#pragma unroll
    for (int rr = 0; rr < 4; ++rr) {
      const float A = scale * o[rr].x;
      const float B = scale * o[rr].y;
      sA += A; sB += B;
      sAA += A * A; sBB += B * B; sAB += A * B;
    }
  }

  // ---- wave shfl reduction -> 4 wave partials -> 5 stores (or atomics fallback) ----
  double v[5] = {(double)sA, (double)sB, (double)sAA, (double)sBB, (double)sAB};
#pragma unroll
  for (int off = 32; off > 0; off >>= 1) {
#pragma unroll
    for (int k = 0; k < 5; ++k) v[k] += __shfl_down(v[k], off, 64);
  }
  const int lane = tid & 63, wv = tid >> 6;
  if (lane == 0) {
#pragma unroll
    for (int k = 0; k < 5; ++k) sm.wred[wv * 5 + k] = v[k];
  }
  __syncthreads();
  if (tid == 0) {
    if (useStore) {
#pragma unroll
      for (int k = 0; k < 5; ++k)
        accn[k] = sm.wred[k] + sm.wred[5 + k] + sm.wred[10 + k] + sm.wred[15 + k];
    } else {
#pragma unroll
      for (int k = 0; k < 5; ++k)
        atomicAdd(&accn[k], sm.wred[k] + sm.wred[5 + k] + sm.wred[10 + k] + sm.wred[15 + k]);
    }
  }
}

__global__ __launch_bounds__(256, 5) void ssim_main(const float* __restrict__ xp,
                                                    const float* __restrict__ yp,
                                                    double* __restrict__ acc,
                                                    int nslot, int useStore) {
  __shared__ SharedMem sm;
  const int bid = blockIdx.x;
  const int n = bid & 7;            // sample == XCD round-robin -> per-XCD L2 affinity
  const int tile = bid >> 3;        // consecutive tiles of one sample per XCD
  const int tc = tile & 31;
  const int tr = tile >> 5;
  const int oy = tr * 32;
  const int ox = tc * 32;
  const int slot = tile & (nslot - 1);
  double* accn = acc + (n * nslot + slot) * 5;
  switch (n) {
    case 0: body<1>(sm, oy, ox, tr, tc, xp, yp, accn, useStore); break;
    case 1: body<2>(sm, oy, ox, tr, tc, xp, yp, accn, useStore); break;
    case 2: body<3>(sm, oy, ox, tr, tc, xp, yp, accn, useStore); break;
    case 3: body<4>(sm, oy, ox, tr, tc, xp, yp, accn, useStore); break;
    case 4: body<5>(sm, oy, ox, tr, tc, xp, yp, accn, useStore); break;
    case 5: body<6>(sm, oy, ox, tr, tc, xp, yp, accn, useStore); break;
    case 6: body<7>(sm, oy, ox, tr, tc, xp, yp, accn, useStore); break;
    default: body<8>(sm, oy, ox, tr, tc, xp, yp, accn, useStore); break;
  }
}

__global__ __launch_bounds__(1024) void ssim_final(const double* __restrict__ acc,
                                                   float* __restrict__ out, int nslot) {
  // 1024 threads = 8 samples x 128 lanes; lane l sums slots l, l+128, ...
  __shared__ double wp[16][5];
  __shared__ double terms[8];
  const int tid = threadIdx.x;
  const int s = tid >> 7;
  const int l = tid & 127;
  double v[5] = {0.0, 0.0, 0.0, 0.0, 0.0};
  for (int slot = l; slot < nslot; slot += 128) {
    const double* p = acc + (size_t)(s * nslot + slot) * 5;
#pragma unroll
    for (int k = 0; k < 5; ++k) v[k] += p[k];
  }
#pragma unroll
  for (int off = 32; off > 0; off >>= 1) {
#pragma unroll
    for (int k = 0; k < 5; ++k) v[k] += __shfl_down(v[k], off, 64);
  }
  if ((tid & 63) == 0) {
#pragma unroll
    for (int k = 0; k < 5; ++k) wp[tid >> 6][k] = v[k];
  }
  __syncthreads();
  if (tid < 8) {
    double u[5];
#pragma unroll
    for (int k = 0; k < 5; ++k) u[k] = wp[2 * tid][k] + wp[2 * tid + 1][k];
    const double C1 = 6.5025;     // (0.01*255)^2
    const double C2 = 58.5225;    // (0.03*255)^2
    const double N = 1048576.0;
    const double mA = u[0] / N, mB = u[1] / N;
    const double varA = (u[2] - N * mA * mA) / (N - 1.0);
    const double varB = (u[3] - N * mB * mB) / (N - 1.0);
    const double cov  = (u[4] - N * mA * mB) / (N - 1.0);
    terms[tid] = ((2.0 * mA * mB + C1) * (2.0 * cov + C2)) /
                 ((mA * mA + mB * mB + C1) * (varA * varA + varB * varB + C2));
  }
  __syncthreads();
  if (tid == 0) {
    double tot = 0.0;
    for (int i = 0; i < 8; ++i) tot += terms[i];
    out[0] = (float)tot;
  }
}

extern "C" void kernel_launch(void* const* d_in, const int* in_sizes, int n_in,
                              void* d_out, int out_size, void* d_ws, size_t ws_size,
                              hipStream_t stream) {
  const float* x = (const float*)d_in[0];
  const float* y = (const float*)d_in[1];
  double* acc = (double*)d_ws;
  float* out = (float*)d_out;

  // Per-tile private slots (no zeroing, no atomics) if the workspace allows:
  const size_t need = (size_t)8 * 1024 * 5 * sizeof(double);   // 320 KB
  const int bigws = ws_size >= need;
  const int nslot = bigws ? 1024 : 64;

  if (!bigws) ssim_zero<<<1, 256, 0, stream>>>(acc);
  ssim_main<<<8192, 256, 0, stream>>>(x, y, acc, nslot, bigws);
  ssim_final<<<1, 1024, 0, stream>>>(acc, out, nslot);
}

// Round 5
// 229.014 us; speedup vs baseline: 1.2029x; 1.0319x over previous
//
#include <hip/hip_runtime.h>

// SSIM-like loss, factored form:
//   term_n uses 3^n * (ZrV)^(n+1) (ZcH)^(n+1) (channel_sum): ONE vertical and ONE
//   horizontal (2h+1)-tap conv with exact edge-clipped weight rows (compile-time
//   __constant__ table). Geometry: 32x32 output tile, 48x48 window, LDS 20,480 B.
//   R5: XCD-BALANCED + L2-AFFINE mapping. With n=bid&7, XCD k ran only sample k;
//   work ~ T=2H+1 in {3..17} -> XCD7 did 5.7x XCD0's conv work -> tail imbalance
//   (occupancy 42% with all pipes idle). New mapping: sample pairs (p, 7-p) have
//   equal T-sum (20); XCD (2p+h) runs tiles [h*512, h*512+512) of sample p, then
//   the same range of sample 7-p. Balanced totals per XCD, consecutive tiles of
//   ONE sample at any time (keeps the halo L2 reuse that R3 broke: FETCH 98 MB,
//   not 316 MB). Load phase: R4's MLP-batched 3-channel-pass (kept unchanged).
//   __launch_bounds__(256,5): empirically no spill ((256,8) spilled 33 MB in R1).

typedef float v2f __attribute__((ext_vector_type(2)));
typedef float v4f __attribute__((ext_vector_type(4)));

#define BSTR 50     // buf float2 stride (even -> 16B-aligned rows for b128)

#define PC 0.19487473f
#define QC 0.23021731f

// ---- compile-time clipped 1-D weight rows: w[H-1][d*T + k], T = 2H+1,
//      d = dist to edge (0..H-1), d = H = interior row.
struct WtTables { float w[8][153]; };
static constexpr WtTables make_tables() {
  WtTables t{};
  for (int H = 1; H <= 8; ++H) {
    const int T = 2 * H + 1;
    for (int d = 0; d <= H; ++d) {
      float Wd[17] = {};
      for (int k = 0; k < T; ++k) Wd[k] = (k == H) ? 1.f : 0.f;
      const int kmin = H - d;
      for (int m = 0; m < H; ++m) {
        float prev = 0.f;
        for (int k = kmin; k < T; ++k) {
          const float cur = Wd[k];
          const float nxt = (k < T - 1) ? Wd[k + 1] : 0.f;
          Wd[k] = QC * cur + PC * (prev + nxt);
          prev = cur;
        }
      }
      for (int k = 0; k < T; ++k) t.w[H - 1][d * T + k] = Wd[k];
    }
  }
  return t;
}
__constant__ WtTables WTAB = make_tables();

struct SharedMem {
  v2f buf[48 * BSTR];   // 19,200 B  input window -> H output (in place)
  double wred[4 * 5];   //    160 B  per-wave partials
  float Wt[153];        //    612 B  clipped weight rows (edge blocks only)
};                      // 19,972 B -> 20,480 granule -> 8 blocks/CU

__global__ __launch_bounds__(256) void ssim_zero(double* acc) {
  for (int i = threadIdx.x; i < 8 * 64 * 5; i += 256) acc[i] = 0.0;
}

template <int H>
__device__ __forceinline__ void body(SharedMem& sm, int oy, int ox, int tr, int tc,
                                     const float* __restrict__ xp,
                                     const float* __restrict__ yp,
                                     double* __restrict__ accn, int useStore) {
  constexpr int T = 2 * H + 1;
  constexpr int n = H - 1;
  constexpr int R0 = 8 - H, R1 = 39 + H;            // used window rows (0..47)
  const int tid = threadIdx.x;
  const bool rowEdge = (tr == 0) | (tr == 31);
  const bool colEdge = (tc == 0) | (tc == 31);

  // ---- load phase: MLP-batched. Cells A=tid, B=tid+256 (of 576 = 48 rows x 12
  //      4-float chunks); 3 channel passes accumulate into LDS (thread-private
  //      cells, same-wave DS ops are in-order -> no barrier needed between passes).
  //      Pass0+pass1 loads (8 v4f) issue before the first vmcnt wait; pass2 issues
  //      while pass1 is in flight. Cell C (tid<64) serial afterward.
  {
    constexpr int CC0 = (8 - H) >> 2, CC1 = (39 + H) >> 2;   // used 4-cell chunks
    const size_t base = (size_t)n * 3145728u;
    const int cA = tid, cB = tid + 256;
    const int rowA = cA / 12, c4A = cA - rowA * 12;
    const int rowB = cB / 12, c4B = cB - rowB * 12;
    const int gyA = oy + rowA - 8, gxA = ox + c4A * 4 - 8;
    const int gyB = oy + rowB - 8, gxB = ox + c4B * 4 - 8;
    const bool uA = (rowA >= R0) & (rowA <= R1) & (c4A >= CC0) & (c4A <= CC1);
    const bool uB = (rowB >= R0) & (rowB <= R1) & (c4B >= CC0) & (c4B <= CC1);
    const bool okA = uA & (((unsigned)gyA < 1024u) & ((unsigned)gxA < 1024u));
    const bool okB = uB & (((unsigned)gyB < 1024u) & ((unsigned)gxB < 1024u));
    const size_t offA = okA ? base + (size_t)gyA * 1024u + (unsigned)gxA : base;
    const size_t offB = okB ? base + (size_t)gyB * 1024u + (unsigned)gxB : base;
    const v4f* pxA = (const v4f*)(xp + offA);
    const v4f* pyA = (const v4f*)(yp + offA);
    const v4f* pxB = (const v4f*)(xp + offB);
    const v4f* pyB = (const v4f*)(yp + offB);
    v4f* dA = (v4f*)(sm.buf + rowA * BSTR + c4A * 4);
    v4f* dB = (v4f*)(sm.buf + rowB * BSTR + c4B * 4);

    v4f xa0, ya0, xb0, yb0, xa1, ya1, xb1, yb1;
    if (okA) { xa0 = pxA[0]; ya0 = pyA[0]; }                   // ch0 issue
    if (okB) { xb0 = pxB[0]; yb0 = pyB[0]; }
    if (okA) { xa1 = pxA[262144]; ya1 = pyA[262144]; }         // ch1 issue
    if (okB) { xb1 = pxB[262144]; yb1 = pyB[262144]; }

    // pass 0 consume (waits ch0 only; ch1 stays in flight)
    if (uA) {
      v4f sx = {0.f, 0.f, 0.f, 0.f}, sy = {0.f, 0.f, 0.f, 0.f};
      if (okA) { sx = xa0; sy = ya0; }
      dA[0] = (v4f){sx.x, sy.x, sx.y, sy.y};
      dA[1] = (v4f){sx.z, sy.z, sx.w, sy.w};
    }
    if (uB) {
      v4f sx = {0.f, 0.f, 0.f, 0.f}, sy = {0.f, 0.f, 0.f, 0.f};
      if (okB) { sx = xb0; sy = yb0; }
      dB[0] = (v4f){sx.x, sy.x, sx.y, sy.y};
      dB[1] = (v4f){sx.z, sy.z, sx.w, sy.w};
    }
    // ch2 issue (while ch1 in flight)
    v4f xa2, ya2, xb2, yb2;
    if (okA) { xa2 = pxA[524288]; ya2 = pyA[524288]; }
    if (okB) { xb2 = pxB[524288]; yb2 = pyB[524288]; }
    // pass 1 consume (LDS accumulate)
    if (okA) {
      dA[0] += (v4f){xa1.x, ya1.x, xa1.y, ya1.y};
      dA[1] += (v4f){xa1.z, ya1.z, xa1.w, ya1.w};
    }
    if (okB) {
      dB[0] += (v4f){xb1.x, yb1.x, xb1.y, yb1.y};
      dB[1] += (v4f){xb1.z, yb1.z, xb1.w, yb1.w};
    }
    // pass 2 consume
    if (okA) {
      dA[0] += (v4f){xa2.x, ya2.x, xa2.y, ya2.y};
      dA[1] += (v4f){xa2.z, ya2.z, xa2.w, ya2.w};
    }
    if (okB) {
      dB[0] += (v4f){xb2.x, yb2.x, xb2.y, yb2.y};
      dB[1] += (v4f){xb2.z, yb2.z, xb2.w, yb2.w};
    }
    // cell C: chunks 512..575 (rows 42..47), one wave, serial old-style
    if (tid < 64) {
      const int cC = tid + 512;
      const int rowC = cC / 12, c4C = cC - rowC * 12;
      if (rowC >= R0 && rowC <= R1 && c4C >= CC0 && c4C <= CC1) {
        const int gyC = oy + rowC - 8, gxC = ox + c4C * 4 - 8;
        v4f sx = {0.f, 0.f, 0.f, 0.f}, sy = {0.f, 0.f, 0.f, 0.f};
        if (((unsigned)gyC < 1024u) && ((unsigned)gxC < 1024u)) {
          const size_t off = base + (size_t)gyC * 1024u + (unsigned)gxC;
          const v4f* px = (const v4f*)(xp + off);
          const v4f* py = (const v4f*)(yp + off);
          sx = px[0] + px[262144] + px[524288];
          sy = py[0] + py[262144] + py[524288];
        }
        v4f* d = (v4f*)(sm.buf + rowC * BSTR + c4C * 4);
        d[0] = (v4f){sx.x, sy.x, sx.y, sy.y};
        d[1] = (v4f){sx.z, sy.z, sx.w, sy.w};
      }
    }
  }
  // ---- edge blocks stage the weight table in LDS (dynamic per-lane indexing) ----
  if (rowEdge | colEdge) {
    for (int i = tid; i < (H + 1) * T; i += 256) sm.Wt[i] = WTAB.w[n][i];
  }
  __syncthreads();

  // ---- H pass IN PLACE: wave g owns col-group g (8 out cols), lane = window row ----
  {
    const int g = tid >> 6;              // col-group 0..3 (wave-uniform)
    const int i0 = tid & 63;             // window row
    constexpr int I0 = (8 - H) >> 1, I1 = (15 + H) >> 1;   // b128 read range
    const bool val = (i0 >= R0) & (i0 <= R1);
    v2f o[8] = {};
    if (val) {
      const v4f* s4 = (const v4f*)(sm.buf + i0 * BSTR + g * 8);
      v2f win[24];
#pragma unroll
      for (int i = I0; i <= I1; ++i) {
        const v4f t = s4[i];
        win[2 * i] = (v2f){t.x, t.y};
        win[2 * i + 1] = (v2f){t.z, t.w};
      }
      if (!colEdge) {
#pragma unroll
        for (int k = 0; k < T; ++k) {
          const float cw = WTAB.w[n][H * T + k];   // compile-time-constant index
#pragma unroll
          for (int j = 0; j < 8; ++j)
            o[j] += cw * win[j + k + 8 - H];
        }
      } else {
        int A0[8], sg[8];
#pragma unroll
        for (int j = 0; j < 8; ++j) {
          const int gx = ox + g * 8 + j;
          int dd = H, rv = 0;
          if (gx < H) dd = gx;
          else if (gx > 1023 - H) { dd = 1023 - gx; rv = 1; }
          A0[j] = dd * T + (rv ? 2 * H : 0);
          sg[j] = rv ? -1 : 1;
        }
#pragma unroll
        for (int j = 0; j < 8; ++j)
          for (int k = 0; k < T; ++k)
            o[j] += sm.Wt[A0[j] + sg[j] * k] * win[j + k + 8 - H];
      }
    }
    __syncthreads();                       // all reads done before any write
    if (val) {
      v4f* d = (v4f*)(sm.buf + i0 * BSTR + g * 8 + 8);
#pragma unroll
      for (int jj = 0; jj < 4; ++jj)
        d[jj] = (v4f){o[2 * jj].x, o[2 * jj].y, o[2 * jj + 1].x, o[2 * jj + 1].y};
    }
  }
  __syncthreads();

  // ---- V pass + fp32 moments: 4 contiguous rows/thread from register window ----
  constexpr float scales[8] = {1.f, 3.f, 9.f, 27.f, 81.f, 243.f, 729.f, 2187.f};
  const float scale = scales[n];
  float sA = 0.f, sB = 0.f, sAA = 0.f, sBB = 0.f, sAB = 0.f;
  {
    const int jt = tid & 31;
    const int iv = tid >> 5;             // 0..7 -> out rows 4iv..4iv+3
    constexpr int C0 = 8 - H, C1 = 11 + H;
    v2f vwin[20];
#pragma unroll
    for (int c = C0; c <= C1; ++c)
      vwin[c] = sm.buf[(4 * iv + c) * BSTR + 8 + jt];
    v2f o[4] = {};
    if (!rowEdge) {
#pragma unroll
      for (int k = 0; k < T; ++k) {
        const float cw = WTAB.w[n][H * T + k];   // compile-time-constant index
#pragma unroll
        for (int rr = 0; rr < 4; ++rr)
          o[rr] += cw * vwin[rr + k + 8 - H];
      }
    } else {
#pragma unroll
      for (int rr = 0; rr < 4; ++rr) {
        const int gy = oy + 4 * iv + rr;
        int dd = H, rv = 0;
        if (gy < H) dd = gy;
        else if (gy > 1023 - H) { dd = 1023 - gy; rv = 1; }
        const int A0 = dd * T + (rv ? 2 * H : 0);
        const int s = rv ? -1 : 1;
        for (int k = 0; k < T; ++k)
          o[rr] += sm.Wt[A0 + s * k] * vwin[rr + k + 8 - H];
      }
    }
#pragma unroll
    for (int rr = 0; rr < 4; ++rr) {
      const float A = scale * o[rr].x;
      const float B = scale * o[rr].y;
      sA += A; sB += B;
      sAA += A * A; sBB += B * B; sAB += A * B;
    }
  }

  // ---- wave shfl reduction -> 4 wave partials -> 5 stores (or atomics fallback) ----
  double v[5] = {(double)sA, (double)sB, (double)sAA, (double)sBB, (double)sAB};
#pragma unroll
  for (int off = 32; off > 0; off >>= 1) {
#pragma unroll
    for (int k = 0; k < 5; ++k) v[k] += __shfl_down(v[k], off, 64);
  }
  const int lane = tid & 63, wv = tid >> 6;
  if (lane == 0) {
#pragma unroll
    for (int k = 0; k < 5; ++k) sm.wred[wv * 5 + k] = v[k];
  }
  __syncthreads();
  if (tid == 0) {
    if (useStore) {
#pragma unroll
      for (int k = 0; k < 5; ++k)
        accn[k] = sm.wred[k] + sm.wred[5 + k] + sm.wred[10 + k] + sm.wred[15 + k];
    } else {
#pragma unroll
      for (int k = 0; k < 5; ++k)
        atomicAdd(&accn[k], sm.wred[k] + sm.wred[5 + k] + sm.wred[10 + k] + sm.wred[15 + k]);
    }
  }
}

__global__ __launch_bounds__(256, 5) void ssim_main(const float* __restrict__ xp,
                                                    const float* __restrict__ yp,
                                                    double* __restrict__ acc,
                                                    int nslot, int useStore) {
  __shared__ SharedMem sm;
  // XCD-balanced + L2-affine bijection (XCD = bid&7 via round-robin dispatch):
  //   pair p = (0,7),(1,6),(2,5),(3,4) -> equal T-sum (20) per XCD.
  //   XCD 2p+h runs tiles [h*512, (h+1)*512) of sample p, then of sample 7-p.
  const int bid = blockIdx.x;
  const int xcd = bid & 7;
  const int j = bid >> 3;           // 0..1023: position in this XCD's stream
  const int p = xcd >> 1;           // pair index 0..3
  const int h = xcd & 1;            // which half of each sample this XCD owns
  const bool second = j >= 512;
  const int n = second ? 7 - p : p;
  const int tile = h * 512 + (second ? j - 512 : j);
  const int tc = tile & 31;
  const int tr = tile >> 5;
  const int oy = tr * 32;
  const int ox = tc * 32;
  const int slot = tile & (nslot - 1);
  double* accn = acc + (n * nslot + slot) * 5;
  switch (n) {
    case 0: body<1>(sm, oy, ox, tr, tc, xp, yp, accn, useStore); break;
    case 1: body<2>(sm, oy, ox, tr, tc, xp, yp, accn, useStore); break;
    case 2: body<3>(sm, oy, ox, tr, tc, xp, yp, accn, useStore); break;
    case 3: body<4>(sm, oy, ox, tr, tc, xp, yp, accn, useStore); break;
    case 4: body<5>(sm, oy, ox, tr, tc, xp, yp, accn, useStore); break;
    case 5: body<6>(sm, oy, ox, tr, tc, xp, yp, accn, useStore); break;
    case 6: body<7>(sm, oy, ox, tr, tc, xp, yp, accn, useStore); break;
    default: body<8>(sm, oy, ox, tr, tc, xp, yp, accn, useStore); break;
  }
}

__global__ __launch_bounds__(1024) void ssim_final(const double* __restrict__ acc,
                                                   float* __restrict__ out, int nslot) {
  // 1024 threads = 8 samples x 128 lanes; lane l sums slots l, l+128, ...
  __shared__ double wp[16][5];
  __shared__ double terms[8];
  const int tid = threadIdx.x;
  const int s = tid >> 7;
  const int l = tid & 127;
  double v[5] = {0.0, 0.0, 0.0, 0.0, 0.0};
  for (int slot = l; slot < nslot; slot += 128) {
    const double* p = acc + (size_t)(s * nslot + slot) * 5;
#pragma unroll
    for (int k = 0; k < 5; ++k) v[k] += p[k];
  }
#pragma unroll
  for (int off = 32; off > 0; off >>= 1) {
#pragma unroll
    for (int k = 0; k < 5; ++k) v[k] += __shfl_down(v[k], off, 64);
  }
  if ((tid & 63) == 0) {
#pragma unroll
    for (int k = 0; k < 5; ++k) wp[tid >> 6][k] = v[k];
  }
  __syncthreads();
  if (tid < 8) {
    double u[5];
#pragma unroll
    for (int k = 0; k < 5; ++k) u[k] = wp[2 * tid][k] + wp[2 * tid + 1][k];
    const double C1 = 6.5025;     // (0.01*255)^2
    const double C2 = 58.5225;    // (0.03*255)^2
    const double N = 1048576.0;
    const double mA = u[0] / N, mB = u[1] / N;
    const double varA = (u[2] - N * mA * mA) / (N - 1.0);
    const double varB = (u[3] - N * mB * mB) / (N - 1.0);
    const double cov  = (u[4] - N * mA * mB) / (N - 1.0);
    terms[tid] = ((2.0 * mA * mB + C1) * (2.0 * cov + C2)) /
                 ((mA * mA + mB * mB + C1) * (varA * varA + varB * varB + C2));
  }
  __syncthreads();
  if (tid == 0) {
    double tot = 0.0;
    for (int i = 0; i < 8; ++i) tot += terms[i];
    out[0] = (float)tot;
  }
}

extern "C" void kernel_launch(void* const* d_in, const int* in_sizes, int n_in,
                              void* d_out, int out_size, void* d_ws, size_t ws_size,
                              hipStream_t stream) {
  const float* x = (const float*)d_in[0];
  const float* y = (const float*)d_in[1];
  double* acc = (double*)d_ws;
  float* out = (float*)d_out;

  // Per-tile private slots (no zeroing, no atomics) if the workspace allows:
  const size_t need = (size_t)8 * 1024 * 5 * sizeof(double);   // 320 KB
  const int bigws = ws_size >= need;
  const int nslot = bigws ? 1024 : 64;

  if (!bigws) ssim_zero<<<1, 256, 0, stream>>>(acc);
  ssim_main<<<8192, 256, 0, stream>>>(x, y, acc, nslot, bigws);
  ssim_final<<<1, 1024, 0, stream>>>(acc, out, nslot);
}